// Round 4
// baseline (326.117 us; speedup 1.0000x reference)
//
#include <hip/hip_runtime.h>
#include <math.h>

// EdgeConv: B=4, C=64, N=32768, k=16, O=64
// U = (W1[:,:64]-W1[:,64:]) @ x + b1 ; V = W1[:,64:] @ x   (per point, bf16-stored)
// h1[b,n,k,o] = U[b,n,o] + V[b,idx[b,n,k],o]  (f32 add of bf16 values)
// BN affine: relu(a*h + c). Layer 2 via bf16 MFMA 16x16x32 (16 neighbors = tile rows).
// k_main fuses gather -> BN1+relu -> MFMA -> {BN2 stats, max_k -> Mx}.
// k_out applies BN2+relu (monotone, a2>0) + transposed write.

#define EPSV 1e-5f
constexpr int Cc = 64;
constexpr int Nn = 32768;
constexpr int BN = 131072;                     // B*N
constexpr float TOTF = 2097152.0f;             // B*N*k

typedef __attribute__((ext_vector_type(8))) short short8;
typedef __attribute__((ext_vector_type(8))) unsigned short ushort8;
typedef __attribute__((ext_vector_type(4))) float floatx4;

__device__ __forceinline__ unsigned short f2bf(float f) {
  __bf16 b = (__bf16)f;                        // RNE fptrunc
  return __builtin_bit_cast(unsigned short, b);
}
__device__ __forceinline__ short f2bfs(float f) {
  __bf16 b = (__bf16)f;
  return __builtin_bit_cast(short, b);
}
__device__ __forceinline__ float bf2f(unsigned short u) {
  union { unsigned u; float f; } x; x.u = ((unsigned)u) << 16; return x.f;
}

// ---------------- K1: U,V precompute (f32 compute, bf16 store) ----------------
__global__ __launch_bounds__(256) void k_uv(const float* __restrict__ x,
                                            const float* __restrict__ W1,
                                            const float* __restrict__ b1,
                                            unsigned short* __restrict__ Ub,
                                            unsigned short* __restrict__ Vb) {
  __shared__ __align__(16) float wdT[64][64];
  __shared__ __align__(16) float wbT[64][64];
  __shared__ __align__(16) float xs[64][64];
  int t = threadIdx.x;
  int b = blockIdx.x >> 9;
  int n0 = (blockIdx.x & 511) << 6;

  for (int i = t; i < 4096; i += 256) {
    int o = i & 63, c = i >> 6;
    float wa = W1[o * 128 + c];
    float wb = W1[o * 128 + 64 + c];
    wdT[c][o] = wa - wb;
    wbT[c][o] = wb;
  }
  const float* xb = x + (size_t)b * Cc * Nn + n0;
  for (int i = t; i < 4096; i += 256) {
    int c = i >> 6, p = i & 63;
    xs[c][p] = xb[(size_t)c * Nn + p];
  }
  __syncthreads();

  int lane = t & 63;
  int pg = t >> 6;
  int pbase = pg * 16;
  float bv = b1[lane];
  float u[16], v[16];
#pragma unroll
  for (int j = 0; j < 16; ++j) { u[j] = bv; v[j] = 0.f; }

  for (int c = 0; c < 64; ++c) {
    float wd = wdT[c][lane];
    float wb = wbT[c][lane];
#pragma unroll
    for (int j4 = 0; j4 < 4; ++j4) {
      float4 xq = *(const float4*)&xs[c][pbase + j4 * 4];
      u[j4 * 4 + 0] += wd * xq.x; v[j4 * 4 + 0] += wb * xq.x;
      u[j4 * 4 + 1] += wd * xq.y; v[j4 * 4 + 1] += wb * xq.y;
      u[j4 * 4 + 2] += wd * xq.z; v[j4 * 4 + 2] += wb * xq.z;
      u[j4 * 4 + 3] += wd * xq.w; v[j4 * 4 + 3] += wb * xq.w;
    }
  }
  size_t base = ((size_t)b * Nn + n0 + pbase) * 64 + lane;
#pragma unroll
  for (int j = 0; j < 16; ++j) {
    Ub[base + (size_t)j * 64] = f2bf(u[j]);
    Vb[base + (size_t)j * 64] = f2bf(v[j]);
  }
}

// ---------------- K2: BN1 stats (gather, bf16 reads) ----------------
__global__ __launch_bounds__(256) void k_stats1(const unsigned short* __restrict__ Ub,
                                                const unsigned short* __restrict__ Vb,
                                                const int* __restrict__ idx,
                                                float* __restrict__ s1,
                                                float* __restrict__ q1) {
  int t = threadIdx.x;
  int lane = t & 63, w = t >> 6;
  int bn0 = blockIdx.x * 4 + w;                // 0..8191
  float s = 0.f, q = 0.f;
#pragma unroll 2
  for (int it = 0; it < 16; ++it) {
    int bn = bn0 + it * 8192;
    size_t vbase = (size_t)(bn >> 15) << 15;
    float u = bf2f(Ub[(size_t)bn * 64 + lane]);
    const int* ip = idx + (size_t)bn * 16;
#pragma unroll
    for (int k4 = 0; k4 < 4; ++k4) {
      int4 i4 = ((const int4*)ip)[k4];
      int mm[4] = {i4.x, i4.y, i4.z, i4.w};
#pragma unroll
      for (int j = 0; j < 4; ++j) {
        float v = bf2f(Vb[(vbase + (size_t)mm[j]) * 64 + lane]);
        float h = u + v;
        s += h; q += h * h;
      }
    }
  }
  __shared__ float rs[4][64], rq[4][64];
  rs[w][lane] = s; rq[w][lane] = q;
  __syncthreads();
  if (w == 0) {
    s = rs[0][lane] + rs[1][lane] + rs[2][lane] + rs[3][lane];
    q = rq[0][lane] + rq[1][lane] + rq[2][lane] + rq[3][lane];
    atomicAdd(&s1[lane], s);
    atomicAdd(&q1[lane], q);
  }
}

// ---------------- finalize BN stats -> affine ----------------
__global__ void k_fin(const float* __restrict__ s, const float* __restrict__ q,
                      const float* __restrict__ g, const float* __restrict__ be,
                      float* __restrict__ a, float* __restrict__ c) {
  int o = threadIdx.x;
  float mean = s[o] / TOTF;
  float var = q[o] / TOTF - mean * mean;
  float av = g[o] / sqrtf(var + EPSV);
  a[o] = av;
  c[o] = be[o] - mean * av;
}

// -------- K4: fused gather -> BN1+relu -> MFMA -> {BN2 stats, max} --------
__global__ __launch_bounds__(256) void k_main(const unsigned short* __restrict__ Ub,
                                              const unsigned short* __restrict__ Vb,
                                              const int* __restrict__ idx,
                                              const float* __restrict__ a1,
                                              const float* __restrict__ c1,
                                              const float* __restrict__ W2,
                                              const float* __restrict__ b2,
                                              float* __restrict__ s2,
                                              float* __restrict__ q2,
                                              float* __restrict__ Mx) {
  __shared__ __align__(16) float mx_lds[64][64];
  __shared__ float sred[4][64], qred[4][64];
  __shared__ int idx_s[1024];
  int t = threadIdx.x;
  int l = t & 63, w = t >> 6;
  int g = l >> 4, r = l & 15;
  int b = blockIdx.x >> 9;
  int n0 = (blockIdx.x & 511) << 6;
  size_t bbase = (size_t)b * Nn;
  size_t bnBase = bbase + n0 + w * 16;
  int g8 = g * 8;

  // stage this block's idx rows (64 points x 16) coalesced
  {
    const int* ip = idx + (bbase + n0) * 16;
    for (int i = t; i < 1024; i += 256) idx_s[i] = ip[i];
  }

  // B-frags: B[k=o][col=p], lane: col = r, k = 8g+i (+32*hh)
  short8 bw[4][2];
#pragma unroll
  for (int tp = 0; tp < 4; ++tp)
#pragma unroll
    for (int hh = 0; hh < 2; ++hh)
#pragma unroll
      for (int i = 0; i < 8; ++i)
        bw[tp][hh][i] = f2bfs(W2[(16 * tp + r) * 64 + 32 * hh + 8 * g + i]);

  float a1v[16], c1v[16];
#pragma unroll
  for (int i = 0; i < 8; ++i) {
    a1v[i] = a1[8 * g + i];          c1v[i] = c1[8 * g + i];
    a1v[8 + i] = a1[32 + 8 * g + i]; c1v[8 + i] = c1[32 + 8 * g + i];
  }
  float b2t[4];
#pragma unroll
  for (int tp = 0; tp < 4; ++tp) b2t[tp] = b2[16 * tp + r];

  __syncthreads();
  int jdx[16];
#pragma unroll
  for (int pt = 0; pt < 16; ++pt) jdx[pt] = idx_s[(w * 16 + pt) * 16 + r];

  ushort8 pva[2], pvb[2], pua[2], pub[2];
#define LDP(PT, S) { \
    const unsigned short* vp = Vb + ((bbase + (size_t)jdx[PT]) << 6); \
    pva[S] = *(const ushort8*)(vp + g8); \
    pvb[S] = *(const ushort8*)(vp + 32 + g8); \
    const unsigned short* up = Ub + ((bnBase + (PT)) << 6); \
    pua[S] = *(const ushort8*)(up + g8); \
    pub[S] = *(const ushort8*)(up + 32 + g8); }

  LDP(0, 0);
  float sa[4] = {0.f, 0.f, 0.f, 0.f}, qa[4] = {0.f, 0.f, 0.f, 0.f};
#pragma unroll
  for (int pt = 0; pt < 16; ++pt) {
    const int cur = pt & 1, nxt = cur ^ 1;
    if (pt < 15) { LDP(pt + 1, nxt); }
    float h[16];
#pragma unroll
    for (int i = 0; i < 8; ++i) {
      h[i]     = bf2f(pua[cur][i]) + bf2f(pva[cur][i]);
      h[8 + i] = bf2f(pub[cur][i]) + bf2f(pvb[cur][i]);
    }
#pragma unroll
    for (int i = 0; i < 16; ++i) h[i] = fmaxf(fmaf(a1v[i], h[i], c1v[i]), 0.f);
    short8 fa0, fa1;
#pragma unroll
    for (int i = 0; i < 8; ++i) { fa0[i] = f2bfs(h[i]); fa1[i] = f2bfs(h[8 + i]); }
#pragma unroll
    for (int tp = 0; tp < 4; ++tp) {
      floatx4 acc = {b2t[tp], b2t[tp], b2t[tp], b2t[tp]};
      acc = __builtin_amdgcn_mfma_f32_16x16x32_bf16(fa0, bw[tp][0], acc, 0, 0, 0);
      acc = __builtin_amdgcn_mfma_f32_16x16x32_bf16(fa1, bw[tp][1], acc, 0, 0, 0);
      float mm = -3.4e38f;
#pragma unroll
      for (int rg = 0; rg < 4; ++rg) {
        float h2 = acc[rg];
        sa[tp] += h2; qa[tp] += h2 * h2;
        mm = fmaxf(mm, h2);
      }
      mm = fmaxf(mm, __shfl_xor(mm, 16));
      mm = fmaxf(mm, __shfl_xor(mm, 32));
      if (g == 0) mx_lds[w * 16 + pt][tp * 16 + r] = mm;
    }
  }
#undef LDP
  // stats reduce: over g (shfl), waves (LDS), then atomic
#pragma unroll
  for (int tp = 0; tp < 4; ++tp) {
    sa[tp] += __shfl_xor(sa[tp], 16); sa[tp] += __shfl_xor(sa[tp], 32);
    qa[tp] += __shfl_xor(qa[tp], 16); qa[tp] += __shfl_xor(qa[tp], 32);
  }
  if (g == 0) {
#pragma unroll
    for (int tp = 0; tp < 4; ++tp) { sred[w][tp * 16 + r] = sa[tp]; qred[w][tp * 16 + r] = qa[tp]; }
  }
  __syncthreads();
  if (w == 0) {
    float s = sred[0][l] + sred[1][l] + sred[2][l] + sred[3][l];
    float q = qred[0][l] + qred[1][l] + qred[2][l] + qred[3][l];
    atomicAdd(&s2[l], s);
    atomicAdd(&q2[l], q);
  }
  float4* dst = (float4*)(Mx + (bbase + n0) * 64);
  const float4* src = (const float4*)mx_lds;
  for (int i = t; i < 1024; i += 256) dst[i] = src[i];
}

// -------- K6: BN2+relu on Mx, transposed write --------
__global__ __launch_bounds__(256) void k_out(const float* __restrict__ Mx,
                                             const float* __restrict__ a2,
                                             const float* __restrict__ c2,
                                             float* __restrict__ out) {
  __shared__ float om[64][65];
  __shared__ float a2s[64], c2s[64];
  int t = threadIdx.x;
  int b = blockIdx.x >> 9;
  int n0 = (blockIdx.x & 511) << 6;
  if (t < 64) { a2s[t] = a2[t]; c2s[t] = c2[t]; }
  __syncthreads();
  const float4* src = (const float4*)(Mx + ((size_t)b * Nn + n0) * 64);
  for (int i = t; i < 1024; i += 256) {
    float4 v4 = src[i];
    int ptl = i >> 4, p0 = (i & 15) * 4;
    float vv[4] = {v4.x, v4.y, v4.z, v4.w};
#pragma unroll
    for (int j = 0; j < 4; ++j) {
      int p = p0 + j;
      om[p][ptl] = fmaxf(a2s[p] * vv[j] + c2s[p], 0.f);
    }
  }
  __syncthreads();
  for (int i = t; i < 1024; i += 256) {
    int p = i >> 4, nn4 = (i & 15) * 4;
    float4 o4 = {om[p][nn4], om[p][nn4 + 1], om[p][nn4 + 2], om[p][nn4 + 3]};
    *(float4*)&out[((size_t)b * 64 + p) * Nn + n0 + nn4] = o4;
  }
}

extern "C" void kernel_launch(void* const* d_in, const int* in_sizes, int n_in,
                              void* d_out, int out_size, void* d_ws, size_t ws_size,
                              hipStream_t stream) {
  const float* x   = (const float*)d_in[0];
  const int*   idx = (const int*)d_in[1];
  const float* W1  = (const float*)d_in[2];
  const float* b1  = (const float*)d_in[3];
  const float* g1  = (const float*)d_in[4];
  const float* be1 = (const float*)d_in[5];
  const float* W2  = (const float*)d_in[6];
  const float* b2  = (const float*)d_in[7];
  const float* g2  = (const float*)d_in[8];
  const float* be2 = (const float*)d_in[9];
  float* out = (float*)d_out;

  unsigned short* Ub = (unsigned short*)d_ws;        // 16 MB
  unsigned short* Vb = Ub + (size_t)BN * 64;         // 16 MB
  float* st = (float*)(Vb + (size_t)BN * 64);        // 512 floats
  float* s1 = st,       *q1 = st + 64,  *a1 = st + 128, *c1 = st + 192;
  float* s2 = st + 256, *q2 = st + 320, *a2 = st + 384, *c2 = st + 448;
  float* Mx = st + 512;                              // 32 MB

  hipMemsetAsync(st, 0, 512 * sizeof(float), stream);
  k_uv<<<2048, 256, 0, stream>>>(x, W1, b1, Ub, Vb);
  k_stats1<<<2048, 256, 0, stream>>>(Ub, Vb, idx, s1, q1);
  k_fin<<<1, 64, 0, stream>>>(s1, q1, g1, be1, a1, c1);
  k_main<<<2048, 256, 0, stream>>>(Ub, Vb, idx, a1, c1, W2, b2, s2, q2, Mx);
  k_fin<<<1, 64, 0, stream>>>(s2, q2, g2, be2, a2, c2);
  k_out<<<2048, 256, 0, stream>>>(Mx, a2, c2, out);
}

// Round 5
// 231.355 us; speedup vs baseline: 1.4096x; 1.4096x over previous
//
#include <hip/hip_runtime.h>
#include <math.h>

// EdgeConv: B=4, C=64, N=32768, k=16, O=64
// U = (W1[:,:64]-W1[:,64:]) @ x + b1 ; V = W1[:,64:] @ x   (bf16-stored)
// h1 = U[n] + V[idx[n,k]] ; BN affine relu(a*h+c); layer2 via bf16 MFMA 16x16x32.
// XCD swizzle: batch b -> XCD pair {2b,2b+1} so V (4MB/batch) stays L2-resident.
// k_main: async gather via global_load_lds (4-slot ring, counted vmcnt, 2-deep).

#define EPSV 1e-5f
constexpr int Cc = 64;
constexpr int Nn = 32768;
constexpr int BN = 131072;                     // B*N
constexpr float TOTF = 2097152.0f;             // B*N*k

typedef __attribute__((ext_vector_type(8))) short short8;
typedef __attribute__((ext_vector_type(8))) unsigned short ushort8;
typedef __attribute__((ext_vector_type(4))) float floatx4;

__device__ __forceinline__ unsigned short f2bf(float f) {
  __bf16 b = (__bf16)f;
  return __builtin_bit_cast(unsigned short, b);
}
__device__ __forceinline__ short f2bfs(float f) {
  __bf16 b = (__bf16)f;
  return __builtin_bit_cast(short, b);
}
__device__ __forceinline__ float bf2f(unsigned short u) {
  union { unsigned u; float f; } x; x.u = ((unsigned)u) << 16; return x.f;
}
__device__ __forceinline__ void gload_lds16(const void* g, void* l) {
  __builtin_amdgcn_global_load_lds(
      (const __attribute__((address_space(1))) unsigned int*)g,
      (__attribute__((address_space(3))) unsigned int*)l, 16, 0, 0);
}
// blockIdx -> (batch, 64-point chunk): batch pinned to XCD pair (bid%8)>>1
__device__ __forceinline__ void swz(int p, int& b, int& n0) {
  b = (p & 7) >> 1;
  n0 = (((p >> 3) << 1) | (p & 1)) << 6;
}

// ---------------- K1: U,V precompute (f32 compute, bf16 store) ----------------
__global__ __launch_bounds__(256) void k_uv(const float* __restrict__ x,
                                            const float* __restrict__ W1,
                                            const float* __restrict__ b1,
                                            unsigned short* __restrict__ Ub,
                                            unsigned short* __restrict__ Vb) {
  __shared__ __align__(16) float wdT[64][64];
  __shared__ __align__(16) float wbT[64][64];
  __shared__ __align__(16) float xs[64][64];
  int t = threadIdx.x;
  int b, n0; swz(blockIdx.x, b, n0);

  for (int i = t; i < 4096; i += 256) {
    int o = i & 63, c = i >> 6;
    float wa = W1[o * 128 + c];
    float wb = W1[o * 128 + 64 + c];
    wdT[c][o] = wa - wb;
    wbT[c][o] = wb;
  }
  const float* xb = x + (size_t)b * Cc * Nn + n0;
  for (int i = t; i < 4096; i += 256) {
    int c = i >> 6, p = i & 63;
    xs[c][p] = xb[(size_t)c * Nn + p];
  }
  __syncthreads();

  int lane = t & 63;
  int pg = t >> 6;
  int pbase = pg * 16;
  float bv = b1[lane];
  float u[16], v[16];
#pragma unroll
  for (int j = 0; j < 16; ++j) { u[j] = bv; v[j] = 0.f; }

  for (int c = 0; c < 64; ++c) {
    float wd = wdT[c][lane];
    float wb = wbT[c][lane];
#pragma unroll
    for (int j4 = 0; j4 < 4; ++j4) {
      float4 xq = *(const float4*)&xs[c][pbase + j4 * 4];
      u[j4 * 4 + 0] += wd * xq.x; v[j4 * 4 + 0] += wb * xq.x;
      u[j4 * 4 + 1] += wd * xq.y; v[j4 * 4 + 1] += wb * xq.y;
      u[j4 * 4 + 2] += wd * xq.z; v[j4 * 4 + 2] += wb * xq.z;
      u[j4 * 4 + 3] += wd * xq.w; v[j4 * 4 + 3] += wb * xq.w;
    }
  }
  size_t base = ((size_t)b * Nn + n0 + pbase) * 64 + lane;
#pragma unroll
  for (int j = 0; j < 16; ++j) {
    Ub[base + (size_t)j * 64] = f2bf(u[j]);
    Vb[base + (size_t)j * 64] = f2bf(v[j]);
  }
}

// ---------------- K2: BN1 stats (pair-loads, 2 points per wave-iter) ----------------
__global__ __launch_bounds__(256) void k_stats1(const unsigned short* __restrict__ Ub,
                                                const unsigned short* __restrict__ Vb,
                                                const int* __restrict__ idx,
                                                float* __restrict__ s1g,
                                                float* __restrict__ q1g) {
  __shared__ int idx_s[1024];
  __shared__ float rs[4][64], rq[4][64];
  int t = threadIdx.x;
  int l = t & 63, w = t >> 6;
  int b, n0; swz(blockIdx.x, b, n0);
  size_t bbase = (size_t)b * Nn, bn0 = bbase + n0;
  {
    const int* ip = idx + bn0 * 16;
    for (int i = t; i < 1024; i += 256) idx_s[i] = ip[i];
  }
  __syncthreads();
  int pp = l >> 5, c2 = l & 31;
  const unsigned short* Vbb = Vb + (bbase << 6);
  float s0 = 0.f, s1 = 0.f, q0 = 0.f, q1 = 0.f;
  for (int it = 0; it < 8; ++it) {
    int ptl = w * 16 + it * 2 + pp;
    unsigned up = *(const unsigned*)&Ub[((bn0 + ptl) << 6) + c2 * 2];
    float u0 = bf2f((unsigned short)up), u1 = bf2f((unsigned short)(up >> 16));
    const int* ips = &idx_s[ptl * 16];
#pragma unroll
    for (int kk = 0; kk < 16; kk += 4) {
      int4 jj = *(const int4*)&ips[kk];
      int ja[4] = {jj.x, jj.y, jj.z, jj.w};
#pragma unroll
      for (int m = 0; m < 4; ++m) {
        unsigned vp = *(const unsigned*)&Vbb[((size_t)ja[m] << 6) + c2 * 2];
        float h0 = u0 + bf2f((unsigned short)vp);
        float h1 = u1 + bf2f((unsigned short)(vp >> 16));
        s0 += h0; q0 += h0 * h0; s1 += h1; q1 += h1 * h1;
      }
    }
  }
  s0 += __shfl_xor(s0, 32); q0 += __shfl_xor(q0, 32);
  s1 += __shfl_xor(s1, 32); q1 += __shfl_xor(q1, 32);
  if (pp == 0) {
    rs[w][2 * c2] = s0; rs[w][2 * c2 + 1] = s1;
    rq[w][2 * c2] = q0; rq[w][2 * c2 + 1] = q1;
  }
  __syncthreads();
  if (w == 0) {
    float s = rs[0][l] + rs[1][l] + rs[2][l] + rs[3][l];
    float q = rq[0][l] + rq[1][l] + rq[2][l] + rq[3][l];
    atomicAdd(&s1g[l], s);
    atomicAdd(&q1g[l], q);
  }
}

// ---------------- finalize BN stats -> affine ----------------
__global__ void k_fin(const float* __restrict__ s, const float* __restrict__ q,
                      const float* __restrict__ g, const float* __restrict__ be,
                      float* __restrict__ a, float* __restrict__ c) {
  int o = threadIdx.x;
  float mean = s[o] / TOTF;
  float var = q[o] / TOTF - mean * mean;
  float av = g[o] / sqrtf(var + EPSV);
  a[o] = av;
  c[o] = be[o] - mean * av;
}

// -------- K4: async-gather -> BN1+relu -> MFMA -> {BN2 stats, max -> Mx(bf16)} --------
__global__ __launch_bounds__(256) void k_main(const unsigned short* __restrict__ Ub,
                                              const unsigned short* __restrict__ Vb,
                                              const int* __restrict__ idx,
                                              const float* __restrict__ a1,
                                              const float* __restrict__ c1,
                                              const float* __restrict__ W2,
                                              const float* __restrict__ b2,
                                              float* __restrict__ s2,
                                              float* __restrict__ q2,
                                              unsigned short* __restrict__ Mxb) {
  __shared__ int idx_s[1024];
  __shared__ float sred[4][64], qred[4][64];
  __shared__ __align__(16) unsigned short vstage[4][4][1024];  // wave, slot, 2KB
  int t = threadIdx.x;
  int l = t & 63, w = t >> 6;
  int g = l >> 4, r = l & 15;
  int b, n0; swz(blockIdx.x, b, n0);
  size_t bbase = (size_t)b * Nn;
  size_t bn0 = bbase + n0;
  size_t wbn = bn0 + w * 16;
  int g8 = g * 8;

  {
    const int* ip = idx + bn0 * 16;
    for (int i = t; i < 1024; i += 256) idx_s[i] = ip[i];
  }

  short8 bw[4][2];
#pragma unroll
  for (int tp = 0; tp < 4; ++tp)
#pragma unroll
    for (int hh = 0; hh < 2; ++hh)
#pragma unroll
      for (int i = 0; i < 8; ++i)
        bw[tp][hh][i] = f2bfs(W2[(16 * tp + r) * 64 + 32 * hh + 8 * g + i]);

  float a1v[16], c1v[16];
#pragma unroll
  for (int i = 0; i < 8; ++i) {
    a1v[i] = a1[8 * g + i];          c1v[i] = c1[8 * g + i];
    a1v[8 + i] = a1[32 + 8 * g + i]; c1v[8 + i] = c1[32 + 8 * g + i];
  }
  float b2t[4];
#pragma unroll
  for (int tp = 0; tp < 4; ++tp) b2t[tp] = b2[16 * tp + r];

  __syncthreads();
  const unsigned short* Vbb = Vb + (bbase << 6);

  auto STAGE = [&](int pt) {
    int jn = idx_s[(w * 16 + pt) * 16 + r];
    const unsigned short* vp = Vbb + ((size_t)jn << 6) + g8;
    unsigned short* sl = &vstage[w][pt & 3][0];
    gload_lds16(vp, sl);
    gload_lds16(vp + 32, sl + 512);
  };
  auto LOADU = [&](int pt, ushort8& lo, ushort8& hi) {
    const unsigned short* up = Ub + ((wbn + pt) << 6);
    lo = *(const ushort8*)(up + g8);
    hi = *(const ushort8*)(up + 32 + g8);
  };

  ushort8 uA_lo, uA_hi, uB_lo, uB_hi;
  STAGE(0); LOADU(0, uA_lo, uA_hi);
  STAGE(1); LOADU(1, uB_lo, uB_hi);

  float sa[4] = {0.f, 0.f, 0.f, 0.f}, qa[4] = {0.f, 0.f, 0.f, 0.f};

#pragma unroll 2
  for (int pt = 0; pt < 16; ++pt) {
    ushort8 nlo, nhi;
    bool pre = (pt + 2 < 16);
    if (pre) { STAGE(pt + 2); LOADU(pt + 2, nlo, nhi); }
    else { nlo = uB_lo; nhi = uB_hi; }
    if (pt < 14)      asm volatile("s_waitcnt vmcnt(8)" ::: "memory");
    else if (pt < 15) asm volatile("s_waitcnt vmcnt(4)" ::: "memory");
    else              asm volatile("s_waitcnt vmcnt(0)" ::: "memory");
    const unsigned short* sl = &vstage[w][pt & 3][0];
    ushort8 v_lo = *(const ushort8*)(sl + l * 8);
    ushort8 v_hi = *(const ushort8*)(sl + 512 + l * 8);
    ushort8 u_lo = (pt & 1) ? uB_lo : uA_lo;
    ushort8 u_hi = (pt & 1) ? uB_hi : uA_hi;

    float h[16];
#pragma unroll
    for (int i = 0; i < 8; ++i) {
      h[i]     = bf2f(u_lo[i]) + bf2f(v_lo[i]);
      h[8 + i] = bf2f(u_hi[i]) + bf2f(v_hi[i]);
    }
#pragma unroll
    for (int i = 0; i < 16; ++i) h[i] = fmaxf(fmaf(a1v[i], h[i], c1v[i]), 0.f);
    short8 fa0, fa1;
#pragma unroll
    for (int i = 0; i < 8; ++i) { fa0[i] = f2bfs(h[i]); fa1[i] = f2bfs(h[8 + i]); }

    float m0, m1, m2, m3;
#pragma unroll
    for (int tp = 0; tp < 4; ++tp) {
      floatx4 acc = {b2t[tp], b2t[tp], b2t[tp], b2t[tp]};
      acc = __builtin_amdgcn_mfma_f32_16x16x32_bf16(fa0, bw[tp][0], acc, 0, 0, 0);
      acc = __builtin_amdgcn_mfma_f32_16x16x32_bf16(fa1, bw[tp][1], acc, 0, 0, 0);
      float mm = -3.4e38f;
#pragma unroll
      for (int rg = 0; rg < 4; ++rg) {
        float h2 = acc[rg];
        sa[tp] += h2; qa[tp] += h2 * h2;
        mm = fmaxf(mm, h2);
      }
      mm = fmaxf(mm, __shfl_xor(mm, 16));
      mm = fmaxf(mm, __shfl_xor(mm, 32));
      if (tp == 0) m0 = mm; else if (tp == 1) m1 = mm;
      else if (tp == 2) m2 = mm; else m3 = mm;
    }
    // lane (g,r) writes channel g*16+r <- max for tp==g
    float mv = (g == 0) ? m0 : (g == 1) ? m1 : (g == 2) ? m2 : m3;
    Mxb[((wbn + pt) << 6) + l] = f2bf(mv);

    if ((pt & 1) == 0) { uA_lo = nlo; uA_hi = nhi; }
    else               { uB_lo = nlo; uB_hi = nhi; }
  }

#pragma unroll
  for (int tp = 0; tp < 4; ++tp) {
    sa[tp] += __shfl_xor(sa[tp], 16); sa[tp] += __shfl_xor(sa[tp], 32);
    qa[tp] += __shfl_xor(qa[tp], 16); qa[tp] += __shfl_xor(qa[tp], 32);
  }
  if (g == 0) {
#pragma unroll
    for (int tp = 0; tp < 4; ++tp) { sred[w][tp * 16 + r] = sa[tp]; qred[w][tp * 16 + r] = qa[tp]; }
  }
  __syncthreads();
  if (w == 0) {
    float s = sred[0][l] + sred[1][l] + sred[2][l] + sred[3][l];
    float q = qred[0][l] + qred[1][l] + qred[2][l] + qred[3][l];
    atomicAdd(&s2[l], s);
    atomicAdd(&q2[l], q);
  }
}

// -------- K6: BN2+relu on Mx(bf16), transposed write --------
__global__ __launch_bounds__(256) void k_out(const unsigned short* __restrict__ Mxb,
                                             const float* __restrict__ a2,
                                             const float* __restrict__ c2,
                                             float* __restrict__ out) {
  __shared__ float om[64][65];
  __shared__ float a2s[64], c2s[64];
  int t = threadIdx.x;
  int b, n0; swz(blockIdx.x, b, n0);
  if (t < 64) { a2s[t] = a2[t]; c2s[t] = c2[t]; }
  __syncthreads();
  const ushort4* src = (const ushort4*)(Mxb + ((size_t)b * Nn + n0) * 64);
  for (int i = t; i < 1024; i += 256) {
    ushort4 v4 = src[i];
    int ptl = i >> 4, p0 = (i & 15) * 4;
    unsigned short vv[4] = {v4.x, v4.y, v4.z, v4.w};
#pragma unroll
    for (int j = 0; j < 4; ++j) {
      int p = p0 + j;
      om[p][ptl] = fmaxf(fmaf(a2s[p], bf2f(vv[j]), c2s[p]), 0.f);
    }
  }
  __syncthreads();
  for (int i = t; i < 1024; i += 256) {
    int p = i >> 4, nn4 = (i & 15) * 4;
    float4 o4 = {om[p][nn4], om[p][nn4 + 1], om[p][nn4 + 2], om[p][nn4 + 3]};
    *(float4*)&out[((size_t)b * 64 + p) * Nn + n0 + nn4] = o4;
  }
}

extern "C" void kernel_launch(void* const* d_in, const int* in_sizes, int n_in,
                              void* d_out, int out_size, void* d_ws, size_t ws_size,
                              hipStream_t stream) {
  const float* x   = (const float*)d_in[0];
  const int*   idx = (const int*)d_in[1];
  const float* W1  = (const float*)d_in[2];
  const float* b1  = (const float*)d_in[3];
  const float* g1  = (const float*)d_in[4];
  const float* be1 = (const float*)d_in[5];
  const float* W2  = (const float*)d_in[6];
  const float* b2  = (const float*)d_in[7];
  const float* g2  = (const float*)d_in[8];
  const float* be2 = (const float*)d_in[9];
  float* out = (float*)d_out;

  unsigned short* Ub = (unsigned short*)d_ws;        // 16 MB
  unsigned short* Vb = Ub + (size_t)BN * 64;         // 16 MB
  float* st = (float*)(Vb + (size_t)BN * 64);        // 512 floats
  float* s1 = st,       *q1 = st + 64,  *a1 = st + 128, *c1 = st + 192;
  float* s2 = st + 256, *q2 = st + 320, *a2 = st + 384, *c2 = st + 448;
  unsigned short* Mxb = (unsigned short*)(st + 512); // 16 MB

  hipMemsetAsync(st, 0, 512 * sizeof(float), stream);
  k_uv<<<2048, 256, 0, stream>>>(x, W1, b1, Ub, Vb);
  k_stats1<<<2048, 256, 0, stream>>>(Ub, Vb, idx, s1, q1);
  k_fin<<<1, 64, 0, stream>>>(s1, q1, g1, be1, a1, c1);
  k_main<<<2048, 256, 0, stream>>>(Ub, Vb, idx, a1, c1, W2, b2, s2, q2, Mxb);
  k_fin<<<1, 64, 0, stream>>>(s2, q2, g2, be2, a2, c2);
  k_out<<<2048, 256, 0, stream>>>(Mxb, a2, c2, out);
}